// Round 2
// baseline (1544.484 us; speedup 1.0000x reference)
//
#include <hip/hip_runtime.h>
#include <hip/hip_cooperative_groups.h>
#include <math.h>

namespace cg = cooperative_groups;

#define NN 2048
#define BATCH 32
#define COLS 64            // 32 sin cols + 32 cos cols
#define DT_STEP 0.1f
#define NSTEPS 10
#define JS 16              // j-splits
#define JR (NN / JS)       // 128
#define RBLK 32            // row blocks of 64 rows
#define GRID_SZ (JS * RBLK)  // 512 blocks

// ---------------------------------------------------------------------------
// init: theta copy + X[j][col]: X[j][b]=sin, X[j][32+b]=cos
// ---------------------------------------------------------------------------
__global__ __launch_bounds__(256) void init_kernel(const float* __restrict__ theta_in,
                                                   float* __restrict__ theta,
                                                   float* __restrict__ X) {
    int t = blockIdx.x * 256 + threadIdx.x;
    int b = t >> 11;
    int i = t & (NN - 1);
    float th = theta_in[t];
    theta[t] = th;
    X[(size_t)i * COLS + b]      = sinf(th);
    X[(size_t)i * COLS + 32 + b] = cosf(th);
}

#define FMA4(A, S, V)                      \
    A.x = fmaf(S, V.x, A.x);               \
    A.y = fmaf(S, V.y, A.y);               \
    A.z = fmaf(S, V.z, A.z);               \
    A.w = fmaf(S, V.w, A.w);

// ---------------------------------------------------------------------------
// GEMM phase: P[s][c][i] = sum_{j in split s} K[i][j] * X[j][c]
// block (s, rb): 64 rows x 64 cols, thread 4x4, transposed store via LDS.
// ---------------------------------------------------------------------------
__device__ __forceinline__ void gemm_phase(const float* __restrict__ K,
                                           const float* __restrict__ X,
                                           float* __restrict__ P,
                                           int bid, int tid) {
    __shared__ float lds[64][65];   // +1 pad -> transpose read is 2-way (free)

    const int s  = bid >> 5;
    const int rb = bid & 31;
    const int cg = tid & 15;
    const int rg = tid >> 4;
    const int c0 = cg * 4;
    const int rowBase = rb * 64 + rg * 4;
    const int j0 = s * JR;

    const float* Kp = K + (size_t)rowBase * NN + j0;
    const float* Xp = X + (size_t)j0 * COLS + c0;

#define LD4X(jj) (*(const float4*)(Xp + (size_t)(jj) * COLS))
#define LD4K(r, jj) (*(const float4*)(Kp + (size_t)(r) * NN + (jj)))

    float4 acc0 = {0.f,0.f,0.f,0.f}, acc1 = {0.f,0.f,0.f,0.f};
    float4 acc2 = {0.f,0.f,0.f,0.f}, acc3 = {0.f,0.f,0.f,0.f};

    float4 x0 = LD4X(0), x1 = LD4X(1), x2 = LD4X(2), x3 = LD4X(3);
    float4 k0 = LD4K(0,0), k1 = LD4K(1,0), k2 = LD4K(2,0), k3 = LD4K(3,0);

#pragma unroll 2
    for (int j = 0; j < JR; j += 4) {
        const int jn = j + ((j + 4 < JR) ? 4 : 0);   // last iter reloads self (branchless)
        float4 nx0 = LD4X(jn + 0), nx1 = LD4X(jn + 1);
        float4 nx2 = LD4X(jn + 2), nx3 = LD4X(jn + 3);
        float4 nk0 = LD4K(0, jn), nk1 = LD4K(1, jn);
        float4 nk2 = LD4K(2, jn), nk3 = LD4K(3, jn);

        FMA4(acc0, k0.x, x0) FMA4(acc0, k0.y, x1) FMA4(acc0, k0.z, x2) FMA4(acc0, k0.w, x3)
        FMA4(acc1, k1.x, x0) FMA4(acc1, k1.y, x1) FMA4(acc1, k1.z, x2) FMA4(acc1, k1.w, x3)
        FMA4(acc2, k2.x, x0) FMA4(acc2, k2.y, x1) FMA4(acc2, k2.z, x2) FMA4(acc2, k2.w, x3)
        FMA4(acc3, k3.x, x0) FMA4(acc3, k3.y, x1) FMA4(acc3, k3.z, x2) FMA4(acc3, k3.w, x3)

        x0 = nx0; x1 = nx1; x2 = nx2; x3 = nx3;
        k0 = nk0; k1 = nk1; k2 = nk2; k3 = nk3;
    }
#undef LD4X
#undef LD4K

    __syncthreads();   // LDS may be in use from a previous phase iteration
    const int lr = rg * 4;
    *(float4*)&lds[lr + 0][c0] = acc0;
    *(float4*)&lds[lr + 1][c0] = acc1;
    *(float4*)&lds[lr + 2][c0] = acc2;
    *(float4*)&lds[lr + 3][c0] = acc3;
    __syncthreads();

    // transposed, coalesced store: P[s][c][rb*64 + io]
    const int io  = tid & 63;
    const int cg2 = tid >> 6;    // 0..3
    float* Pb = P + ((size_t)s * COLS + cg2 * 16) * NN + (size_t)rb * 64 + io;
#pragma unroll
    for (int cc = 0; cc < 16; ++cc)
        Pb[(size_t)cc * NN] = lds[io][cg2 * 16 + cc];
}

// ---------------------------------------------------------------------------
// update phase: coalesced P reads, Kuramoto step, wrap, refresh X.
// 128 active threads per block: t = bid*128 + tid
// ---------------------------------------------------------------------------
__device__ __forceinline__ void update_phase(float* __restrict__ theta,
                                             float* __restrict__ X,
                                             const float* __restrict__ P,
                                             const float* __restrict__ omega,
                                             const float* __restrict__ Kg,
                                             const float* __restrict__ mu,
                                             int bid, int tid) {
    if (tid >= 128) return;
    int t = bid * 128 + tid;
    int b = t >> 11;
    int i = t & (NN - 1);

    float sumS = 0.f, sumC = 0.f;
#pragma unroll
    for (int s = 0; s < JS; ++s) {
        sumS += P[((size_t)s * COLS + b) * NN + i];
        sumC += P[((size_t)s * COLS + 32 + b) * NN + i];
    }

    float g = (Kg[0] / (float)NN) * (mu[0] * 0.5f);
    float th = theta[t];
    float sV = X[(size_t)i * COLS + b];
    float cV = X[(size_t)i * COLS + 32 + b];

    float dth = omega[i] + g * (cV * sumS - sV * sumC);
    float thn = th + DT_STEP * dth;
    float sn = sinf(thn);
    float cn = cosf(thn);
    theta[t] = atan2f(sn, cn);
    X[(size_t)i * COLS + b]      = sn;
    X[(size_t)i * COLS + 32 + b] = cn;
}

// ---------------------------------------------------------------------------
// fused cooperative kernel: 10 steps, 2 grid syncs per step
// ---------------------------------------------------------------------------
__global__ __launch_bounds__(256) void fused_kernel(const float* __restrict__ K,
                                                    float* __restrict__ theta,
                                                    float* __restrict__ X,
                                                    float* __restrict__ P,
                                                    const float* __restrict__ omega,
                                                    const float* __restrict__ Kg,
                                                    const float* __restrict__ mu) {
    cg::grid_group grid = cg::this_grid();
    const int bid = blockIdx.x;
    const int tid = threadIdx.x;
    for (int step = 0; step < NSTEPS; ++step) {
        gemm_phase(K, X, P, bid, tid);
        grid.sync();
        update_phase(theta, X, P, omega, Kg, mu, bid, tid);
        grid.sync();
    }
}

// fallback multi-kernel path (identical math)
__global__ __launch_bounds__(256) void gemm_step_kernel(const float* __restrict__ K,
                                                        const float* __restrict__ X,
                                                        float* __restrict__ P) {
    gemm_phase(K, X, P, blockIdx.x, threadIdx.x);
}
__global__ __launch_bounds__(128) void update_step_kernel(float* __restrict__ theta,
                                                          float* __restrict__ X,
                                                          const float* __restrict__ P,
                                                          const float* __restrict__ omega,
                                                          const float* __restrict__ Kg,
                                                          const float* __restrict__ mu) {
    update_phase(theta, X, P, omega, Kg, mu, blockIdx.x, threadIdx.x);
}

// ---------------------------------------------------------------------------
// coherence
// ---------------------------------------------------------------------------
__global__ __launch_bounds__(256) void coh_kernel(const float* __restrict__ theta,
                                                  float* __restrict__ out) {
    int b = blockIdx.x;
    const float* th = theta + (size_t)b * NN;
    float sc = 0.f, ss = 0.f;
    for (int i = threadIdx.x; i < NN; i += 256) {
        float t = th[i];
        sc += cosf(t);
        ss += sinf(t);
    }
    for (int off = 32; off > 0; off >>= 1) {
        sc += __shfl_down(sc, off);
        ss += __shfl_down(ss, off);
    }
    __shared__ float red[2][4];
    int wave = threadIdx.x >> 6;
    if ((threadIdx.x & 63) == 0) { red[0][wave] = sc; red[1][wave] = ss; }
    __syncthreads();
    if (threadIdx.x == 0) {
        float csum = red[0][0] + red[0][1] + red[0][2] + red[0][3];
        float ssum = red[1][0] + red[1][1] + red[1][2] + red[1][3];
        float cm = csum / (float)NN;
        float sm = ssum / (float)NN;
        out[b] = sqrtf(cm * cm + sm * sm);
    }
}

extern "C" void kernel_launch(void* const* d_in, const int* in_sizes, int n_in,
                              void* d_out, int out_size, void* d_ws, size_t ws_size,
                              hipStream_t stream) {
    const float* K      = (const float*)d_in[1];
    const float* theta0 = (const float*)d_in[0];
    const float* omega  = (const float*)d_in[2];
    const float* Kg     = (const float*)d_in[3];
    const float* mu     = (const float*)d_in[4];

    float* out   = (float*)d_out;
    float* theta = out;                 // BATCH*NN
    float* coh   = out + BATCH * NN;    // BATCH

    float* X = (float*)d_ws;                       // NN x COLS      (512 KB)
    float* P = X + (size_t)NN * COLS;              // JS x COLS x NN (8 MB)

    init_kernel<<<(BATCH * NN) / 256, 256, 0, stream>>>(theta0, theta, X);

    void* args[] = {(void*)&K, (void*)&theta, (void*)&X, (void*)&P,
                    (void*)&omega, (void*)&Kg, (void*)&mu};
    hipError_t e = hipLaunchCooperativeKernel((const void*)fused_kernel,
                                              dim3(GRID_SZ), dim3(256),
                                              args, 0, stream);
    if (e != hipSuccess) {
        // fallback: multi-kernel, same math
        for (int step = 0; step < NSTEPS; ++step) {
            gemm_step_kernel<<<GRID_SZ, 256, 0, stream>>>(K, X, P);
            update_step_kernel<<<GRID_SZ, 128, 0, stream>>>(theta, X, P, omega, Kg, mu);
        }
    }

    coh_kernel<<<BATCH, 256, 0, stream>>>(theta, coh);
}

// Round 3
// 440.948 us; speedup vs baseline: 3.5026x; 3.5026x over previous
//
#include <hip/hip_runtime.h>
#include <math.h>

#define NN 2048
#define BATCH 32
#define COLS 64            // 32 sin cols + 32 cos cols
#define DT_STEP 0.1f
#define NSTEPS 10
#define JS 16              // j-splits
#define JR (NN / JS)       // 128
#define GRID_SZ (JS * 32)  // 512 blocks (32 row-blocks of 64 rows)

// ---------------------------------------------------------------------------
// init: theta copy + X[j][col]: X[j][b]=sin, X[j][32+b]=cos
// ---------------------------------------------------------------------------
__global__ __launch_bounds__(256) void init_kernel(const float* __restrict__ theta_in,
                                                   float* __restrict__ theta,
                                                   float* __restrict__ X) {
    int t = blockIdx.x * 256 + threadIdx.x;
    int b = t >> 11;
    int i = t & (NN - 1);
    float th = theta_in[t];
    theta[t] = th;
    X[(size_t)i * COLS + b]      = sinf(th);
    X[(size_t)i * COLS + 32 + b] = cosf(th);
}

#define FMA4(A, S, V)                      \
    A.x = fmaf(S, V.x, A.x);               \
    A.y = fmaf(S, V.y, A.y);               \
    A.z = fmaf(S, V.z, A.z);               \
    A.w = fmaf(S, V.w, A.w);

// ---------------------------------------------------------------------------
// GEMM: P[s][c][i] = sum_{j in split s} K[i][j] * X[j][c]
// block (s, rb): 64 rows x 64 cols, thread 4x4, double-buffered loads,
// transposed (coalesced) store via padded LDS.
// ---------------------------------------------------------------------------
__global__ __launch_bounds__(256) void gemm_step_kernel(const float* __restrict__ K,
                                                        const float* __restrict__ X,
                                                        float* __restrict__ P) {
    __shared__ float lds[64][65];   // +1 pad: transpose read = 2 lanes/bank (free)

    const int bid = blockIdx.x;
    const int tid = threadIdx.x;
    const int s  = bid >> 5;
    const int rb = bid & 31;
    const int cg = tid & 15;
    const int rg = tid >> 4;
    const int c0 = cg * 4;
    const int rowBase = rb * 64 + rg * 4;
    const int j0 = s * JR;

    const float* Kp = K + (size_t)rowBase * NN + j0;
    const float* Xp = X + (size_t)j0 * COLS + c0;

#define LD4X(jj) (*(const float4*)(Xp + (size_t)(jj) * COLS))
#define LD4K(r, jj) (*(const float4*)(Kp + (size_t)(r) * NN + (jj)))

    float4 acc0 = {0.f,0.f,0.f,0.f}, acc1 = {0.f,0.f,0.f,0.f};
    float4 acc2 = {0.f,0.f,0.f,0.f}, acc3 = {0.f,0.f,0.f,0.f};

    float4 x0 = LD4X(0), x1 = LD4X(1), x2 = LD4X(2), x3 = LD4X(3);
    float4 k0 = LD4K(0,0), k1 = LD4K(1,0), k2 = LD4K(2,0), k3 = LD4K(3,0);

#pragma unroll 2
    for (int j = 0; j < JR; j += 4) {
        const int jn = j + ((j + 4 < JR) ? 4 : 0);   // last iter reloads self
        float4 nx0 = LD4X(jn + 0), nx1 = LD4X(jn + 1);
        float4 nx2 = LD4X(jn + 2), nx3 = LD4X(jn + 3);
        float4 nk0 = LD4K(0, jn), nk1 = LD4K(1, jn);
        float4 nk2 = LD4K(2, jn), nk3 = LD4K(3, jn);

        FMA4(acc0, k0.x, x0) FMA4(acc0, k0.y, x1) FMA4(acc0, k0.z, x2) FMA4(acc0, k0.w, x3)
        FMA4(acc1, k1.x, x0) FMA4(acc1, k1.y, x1) FMA4(acc1, k1.z, x2) FMA4(acc1, k1.w, x3)
        FMA4(acc2, k2.x, x0) FMA4(acc2, k2.y, x1) FMA4(acc2, k2.z, x2) FMA4(acc2, k2.w, x3)
        FMA4(acc3, k3.x, x0) FMA4(acc3, k3.y, x1) FMA4(acc3, k3.z, x2) FMA4(acc3, k3.w, x3)

        x0 = nx0; x1 = nx1; x2 = nx2; x3 = nx3;
        k0 = nk0; k1 = nk1; k2 = nk2; k3 = nk3;
    }
#undef LD4X
#undef LD4K

    const int lr = rg * 4;
    *(float4*)&lds[lr + 0][c0] = acc0;
    *(float4*)&lds[lr + 1][c0] = acc1;
    *(float4*)&lds[lr + 2][c0] = acc2;
    *(float4*)&lds[lr + 3][c0] = acc3;
    __syncthreads();

    // transposed, coalesced store: P[s][c][rb*64 + io]
    const int io  = tid & 63;
    const int cg2 = tid >> 6;    // 0..3
    float* Pb = P + ((size_t)s * COLS + cg2 * 16) * NN + (size_t)rb * 64 + io;
#pragma unroll
    for (int cc = 0; cc < 16; ++cc)
        Pb[(size_t)cc * NN] = lds[io][cg2 * 16 + cc];
}

// ---------------------------------------------------------------------------
// update: coalesced P reads, Kuramoto step, wrap, refresh X.
// t = blockIdx*256 + tid = b*NN + i
// ---------------------------------------------------------------------------
__global__ __launch_bounds__(256) void update_step_kernel(float* __restrict__ theta,
                                                          float* __restrict__ X,
                                                          const float* __restrict__ P,
                                                          const float* __restrict__ omega,
                                                          const float* __restrict__ Kg,
                                                          const float* __restrict__ mu) {
    int t = blockIdx.x * 256 + threadIdx.x;
    int b = t >> 11;
    int i = t & (NN - 1);

    float sumS = 0.f, sumC = 0.f;
#pragma unroll
    for (int s = 0; s < JS; ++s) {
        sumS += P[((size_t)s * COLS + b) * NN + i];
        sumC += P[((size_t)s * COLS + 32 + b) * NN + i];
    }

    float g = (Kg[0] / (float)NN) * (mu[0] * 0.5f);
    float th = theta[t];
    float sV = X[(size_t)i * COLS + b];
    float cV = X[(size_t)i * COLS + 32 + b];

    float dth = omega[i] + g * (cV * sumS - sV * sumC);
    float thn = th + DT_STEP * dth;
    float sn = sinf(thn);
    float cn = cosf(thn);
    theta[t] = atan2f(sn, cn);
    X[(size_t)i * COLS + b]      = sn;
    X[(size_t)i * COLS + 32 + b] = cn;
}

// ---------------------------------------------------------------------------
// coherence
// ---------------------------------------------------------------------------
__global__ __launch_bounds__(256) void coh_kernel(const float* __restrict__ theta,
                                                  float* __restrict__ out) {
    int b = blockIdx.x;
    const float* th = theta + (size_t)b * NN;
    float sc = 0.f, ss = 0.f;
    for (int i = threadIdx.x; i < NN; i += 256) {
        float t = th[i];
        sc += cosf(t);
        ss += sinf(t);
    }
    for (int off = 32; off > 0; off >>= 1) {
        sc += __shfl_down(sc, off);
        ss += __shfl_down(ss, off);
    }
    __shared__ float red[2][4];
    int wave = threadIdx.x >> 6;
    if ((threadIdx.x & 63) == 0) { red[0][wave] = sc; red[1][wave] = ss; }
    __syncthreads();
    if (threadIdx.x == 0) {
        float csum = red[0][0] + red[0][1] + red[0][2] + red[0][3];
        float ssum = red[1][0] + red[1][1] + red[1][2] + red[1][3];
        float cm = csum / (float)NN;
        float sm = ssum / (float)NN;
        out[b] = sqrtf(cm * cm + sm * sm);
    }
}

extern "C" void kernel_launch(void* const* d_in, const int* in_sizes, int n_in,
                              void* d_out, int out_size, void* d_ws, size_t ws_size,
                              hipStream_t stream) {
    const float* theta0 = (const float*)d_in[0];
    const float* K      = (const float*)d_in[1];
    const float* omega  = (const float*)d_in[2];
    const float* Kg     = (const float*)d_in[3];
    const float* mu     = (const float*)d_in[4];

    float* out   = (float*)d_out;
    float* theta = out;                 // BATCH*NN
    float* coh   = out + BATCH * NN;    // BATCH

    float* X = (float*)d_ws;                       // NN x COLS      (512 KB)
    float* P = X + (size_t)NN * COLS;              // JS x COLS x NN (8 MB)

    init_kernel<<<(BATCH * NN) / 256, 256, 0, stream>>>(theta0, theta, X);
    for (int step = 0; step < NSTEPS; ++step) {
        gemm_step_kernel<<<GRID_SZ, 256, 0, stream>>>(K, X, P);
        update_step_kernel<<<(BATCH * NN) / 256, 256, 0, stream>>>(theta, X, P, omega, Kg, mu);
    }
    coh_kernel<<<BATCH, 256, 0, stream>>>(theta, coh);
}